// Round 7
// baseline (158.085 us; speedup 1.0000x reference)
//
#include <hip/hip_runtime.h>
#include <hip/hip_bf16.h>

#define NB   64
#define SL   1024
#define EMB  128
#define NSK  1000
#define NS   2     // i-step parity split

// bf16 table layout in ws (elements):
#define AI_OFF 0
#define BI_OFF 256000
#define AS_OFF 512000
#define BS_OFF 640000
#define TB_ELEMS 768000
#define ACC_BYTE_OFF (TB_ELEMS * 2)   // acc: [NS][NB][SL] float = 512 KB

using short8  = __attribute__((ext_vector_type(8))) short;
using floatx4 = __attribute__((ext_vector_type(4))) float;

// log5(x) = log2(x) * INV_LOG2_5
#define INV_LOG2_5 0.43067655807339306f

__device__ inline unsigned cvt2(float x, float y) {
    float2 f; f.x = x; f.y = y;
    __hip_bfloat162 h = __float22bfloat162_rn(f);
    unsigned u; __builtin_memcpy(&u, &h, sizeof(u));
    return u;
}

// ---- one-time fp32 -> bf16 table conversion (8 elems/thread) ----
extern "C" __global__ __launch_bounds__(256)
void cvt_tables(const float* __restrict__ ai, const float* __restrict__ bi,
                const float* __restrict__ as, const float* __restrict__ bs,
                unsigned short* __restrict__ dst)
{
    const int t = blockIdx.x * 256 + threadIdx.x;   // 96000 threads
    const long e = (long)t * 8;
    const float* src;
    if      (e < 256000) src = ai + e;
    else if (e < 512000) src = bi + (e - 256000);
    else if (e < 640000) src = as + (e - 512000);
    else                 src = bs + (e - 640000);
    float4 f0 = *(const float4*)src;
    float4 f1 = *(const float4*)(src + 4);
    uint4 pk;
    pk.x = cvt2(f0.x, f0.y); pk.y = cvt2(f0.z, f0.w);
    pk.z = cvt2(f1.x, f1.y); pk.w = cvt2(f1.z, f1.w);
    *(uint4*)(dst + e) = pk;
}

// exact fp32 path for duplicate-timestamp pairs (dt==0, i<j):
// contribution = alpha_dot * exp(beta' * 14.306765580733931)   [= -log(1e-10)/log(5)]
__device__ float fixup_pair(const float* __restrict__ air,
                            const float* __restrict__ bir,
                            const float* __restrict__ asr,
                            const float* __restrict__ bsr) {
    float da = 0.f, db = 0.f;
    for (int k = 0; k < EMB; ++k) {
        da += air[k] * asr[k];
        db += bir[k] * bsr[k];
    }
    float beta = fminf(fmaxf(db + 1.f, 0.f), 10.f);
    return da * __expf(beta * 14.30676558073393f);
}

// One independent WAVE per (b, 32-j strip-pair, i-parity). No LDS, no barriers:
// A-fragments load straight from L2-resident bf16 tables into the exact MFMA
// lane layout (m=lane&15, k=quad*8+j). R4/R6 showed the block-synchronous LDS
// structure pinned at ~51 us regardless of LDS traffic; this removes it.
extern "C" __global__ __launch_bounds__(64, 3)
void hawkes_main(const int*   __restrict__ inp,          // (B,4,L) int32
                 const unsigned short* __restrict__ tb,  // bf16 tables
                 float*       __restrict__ acc)          // [NS][NB][SL] partials
{
    const int u    = blockIdx.x;               // 4096 wave-units
    const int jt   = 31 - (u >> 7);            // 32-j tile, heavy first
    const int rem  = u & 127;
    const int b    = rem >> 1;
    const int s    = rem & 1;                  // i-step parity
    const int l    = threadIdx.x;              // 0..63
    const int quad = l >> 4;
    const int col  = l & 15;

    const int* __restrict__ binp = inp + b * 4 * SL;

    const int j0 = jt * 32 + col;              // strip 0
    const int j1 = j0 + 16;                    // strip 1
    const int sk0 = binp[j0],          sk1 = binp[j1];
    const int tj0 = binp[3 * SL + j0], tj1 = binp[3 * SL + j1];

    // ---- B fragments for both strips, both matrices (held in regs) ----
    short8 bfa0[4], bfb0[4], bfa1[4], bfb1[4];
    {
        const unsigned short* p0a = tb + AS_OFF + (long)sk0 * EMB + quad * 8;
        const unsigned short* p0b = tb + BS_OFF + (long)sk0 * EMB + quad * 8;
        const unsigned short* p1a = tb + AS_OFF + (long)sk1 * EMB + quad * 8;
        const unsigned short* p1b = tb + BS_OFF + (long)sk1 * EMB + quad * 8;
#pragma unroll
        for (int ks = 0; ks < 4; ++ks) {
            bfa0[ks] = *(const short8*)(p0a + ks * 32);
            bfb0[ks] = *(const short8*)(p0b + ks * 32);
            bfa1[ks] = *(const short8*)(p1a + ks * 32);
            bfb1[ks] = *(const short8*)(p1b + ks * 32);
        }
    }

    float sum0 = 0.f, sum1 = 0.f;
    const int kmax = 2 * jt + 1;               // i-steps of 16 rows cover [0, 32*jt+32)

    for (int k = s; k <= kmax; k += NS) {
        const int ibase = k * 16;

        // gather this step's A-row base for this lane's m=col (16 rows/wave)
        const int ski   = binp[ibase + col];
        const int li    = binp[2 * SL + ibase + col];
        const long intr = ski + (long)li * NSK;
        const unsigned short* rA = tb + AI_OFF + intr * EMB + quad * 8;
        const unsigned short* rB = tb + BI_OFF + intr * EMB + quad * 8;

        const int4 t4 = *(const int4*)(binp + 3 * SL + ibase + quad * 4);

        floatx4 aa0 = {0.f,0.f,0.f,0.f}, bb0 = {0.f,0.f,0.f,0.f};
        floatx4 aa1 = {0.f,0.f,0.f,0.f}, bb1 = {0.f,0.f,0.f,0.f};
#pragma unroll
        for (int ks = 0; ks < 4; ++ks) {
            short8 av = *(const short8*)(rA + ks * 32);   // A-frag direct from global
            short8 bv = *(const short8*)(rB + ks * 32);
            aa0 = __builtin_amdgcn_mfma_f32_16x16x32_bf16(av, bfa0[ks], aa0, 0, 0, 0);
            aa1 = __builtin_amdgcn_mfma_f32_16x16x32_bf16(av, bfa1[ks], aa1, 0, 0, 0);
            bb0 = __builtin_amdgcn_mfma_f32_16x16x32_bf16(bv, bfb0[ks], bb0, 0, 0, 0);
            bb1 = __builtin_amdgcn_mfma_f32_16x16x32_bf16(bv, bfb1[ks], bb1, 0, 0, 0);
        }

#pragma unroll
        for (int rr = 0; rr < 4; ++rr) {
            const int ti = (rr == 0) ? t4.x : (rr == 1) ? t4.y : (rr == 2) ? t4.z : t4.w;
            // sorted times => (i<j && dt>0) <=> dt>0 ; dt==0 dups handled in finalize
            {
                const int dt = tj0 - ti;
                float lc   = __log2f((float)dt) * (-INV_LOG2_5);
                float beta = fminf(fmaxf(bb0[rr] + 1.f, 0.f), 10.f);
                float arg  = (dt > 0) ? beta * lc : -__builtin_inff();
                sum0 += aa0[rr] * exp2f(arg);
            }
            {
                const int dt = tj1 - ti;
                float lc   = __log2f((float)dt) * (-INV_LOG2_5);
                float beta = fminf(fmaxf(bb1[rr] + 1.f, 0.f), 10.f);
                float arg  = (dt > 0) ? beta * lc : -__builtin_inff();
                sum1 += aa1[rr] * exp2f(arg);
            }
        }
    }

    // reduce the 4 quads holding the same j
    sum0 += __shfl_xor(sum0, 16, 64); sum0 += __shfl_xor(sum0, 32, 64);
    sum1 += __shfl_xor(sum1, 16, 64); sum1 += __shfl_xor(sum1, 32, 64);

    if (quad == 0) {
        float* as_ = acc + (((long)s * NB + b) << 10);
        as_[j0] = sum0;       // write-once per (s,b,j): no init, no atomics
        as_[j1] = sum1;
    }
}

extern "C" __global__ __launch_bounds__(256)
void hawkes_finalize(const int* __restrict__ inp, const float* __restrict__ pbase,
                     const float* __restrict__ sbase,
                     const float* __restrict__ ai, const float* __restrict__ as,
                     const float* __restrict__ bi, const float* __restrict__ bs,
                     const float* __restrict__ acc, float* __restrict__ out)
{
    const int t = blockIdx.x * 256 + threadIdx.x;   // 65536
    const int b = t >> 10, j = t & (SL - 1);
    const int* binp = inp + b * 4 * SL;
    const int tj   = binp[3 * SL + j];
    const int sk_j = binp[j];

    // exact fp32 correction for duplicate-timestamp pairs (adjacent in sorted order)
    float corr = 0.f;
    for (int i = j - 1; i >= 0 && binp[3 * SL + i] == tj; --i) {
        const int ski = binp[i], li = binp[2 * SL + i];
        const long intr = ski + (long)li * NSK;
        corr += fixup_pair(ai + intr * EMB, bi + intr * EMB,
                           as + (long)sk_j * EMB, bs + (long)sk_j * EMB);
    }

    float sum = acc[t] + acc[NB * SL + t] + corr;
    const float x = pbase[binp[SL + j]] + sbase[sk_j] + sum;
    out[t] = 1.f / (1.f + __expf(-x));
}

extern "C" void kernel_launch(void* const* d_in, const int* in_sizes, int n_in,
                              void* d_out, int out_size, void* d_ws, size_t ws_size,
                              hipStream_t stream) {
    const int*   inp = (const int*)d_in[0];
    const float* pb  = (const float*)d_in[1];
    const float* sb  = (const float*)d_in[2];
    const float* ai  = (const float*)d_in[3];
    const float* as  = (const float*)d_in[4];
    const float* bi  = (const float*)d_in[5];
    const float* bs  = (const float*)d_in[6];

    unsigned short* tb  = (unsigned short*)d_ws;
    float*          acc = (float*)((char*)d_ws + ACC_BYTE_OFF);

    cvt_tables<<<dim3(96000 / 256), dim3(256), 0, stream>>>(ai, bi, as, bs, tb);
    hawkes_main<<<dim3(NB * 32 * NS), dim3(64), 0, stream>>>(inp, tb, acc);
    hawkes_finalize<<<dim3(NB * SL / 256), dim3(256), 0, stream>>>(
        inp, pb, sb, ai, as, bi, bs, acc, (float*)d_out);
}